// Round 13
// baseline (335.467 us; speedup 1.0000x reference)
//
#include <hip/hip_runtime.h>
#include <hip/hip_bf16.h>

#define N_NODES 100000
#define N_EDGES 1600000
#define F_IN 20
#define HID 64
#define N_GRAPHS 2000

#define CAP 64          // bucket capacity per node (max degree ~40 << 64)
#define RNG 8           // dst ranges == XCD count (CSR build locality only)
#define RANGE_SZ 12500  // N_NODES / RNG
#define EPB 6400        // edges per block chunk
#define NCHUNK 250      // N_EDGES / EPB

// ---- bf16 helpers (manual RNE pack; storage-only quantization) ----
__device__ __forceinline__ unsigned int f2bf(float f) {
    unsigned int u = __float_as_uint(f);
    return (u + 0x7FFFu + ((u >> 16) & 1u)) >> 16;
}
__device__ __forceinline__ unsigned int pack_bf2(float lo, float hi) {
    return f2bf(lo) | (f2bf(hi) << 16);
}
__device__ __forceinline__ float bf_lo(unsigned int u) { return __uint_as_float(u << 16); }
__device__ __forceinline__ float bf_hi(unsigned int u) { return __uint_as_float(u & 0xFFFF0000u); }

// ---------------- bucket CSR build (range-filtered, XCD-local atomics) ----------------
// NT loads on src/dst: the 12.8 MB/pass edge stream must not evict the
// 3.2 MB dirty bucket window from the XCD's L2 (that eviction was the 6x
// write amplification seen in R12: WRITE 78 MB vs ~13 MB dirtied).

__global__ __launch_bounds__(256) void k_fill_b(const int* __restrict__ src,
                                                const int* __restrict__ dst,
                                                int* __restrict__ cnt,
                                                int* __restrict__ col) {
    int r = blockIdx.x & (RNG - 1);
    int c = blockIdx.x >> 3;
    int lo = r * RANGE_SZ, hi = lo + RANGE_SZ;
    int base = c * EPB;
    for (int i = threadIdx.x; i < EPB; i += 256) {
        int e = base + i;
        int d = __builtin_nontemporal_load(&dst[e]);
        if (d >= lo && d < hi) {
            int s = __builtin_nontemporal_load(&src[e]);
            int pos = atomicAdd(&cnt[d], 1);
            if (pos < CAP) col[(d << 6) + pos] = s;
        }
    }
}

// dinv = 1/sqrt(deg+1)
__global__ void k_dinv(const int* __restrict__ cnt, float* __restrict__ dinv) {
    int v = blockIdx.x * 256 + threadIdx.x;
    if (v < N_NODES) dinv[v] = 1.0f / sqrtf((float)(cnt[v] + 1));
}

// ---------------- layers ----------------

// y1 = bf16( dinv[v] * (x[v,:] @ W) ).  2 nodes per wave: lane i -> node
// vbase+(i>>5), u32 feature slot li = i&31 (feats 2li, 2li+1).
__global__ __launch_bounds__(256) void k_gemm1(const float* __restrict__ x,
                                               const float* __restrict__ W,
                                               const float* __restrict__ dinv,
                                               unsigned int* __restrict__ yb) {
    __shared__ float Ws[F_IN * HID];
    int tid = threadIdx.x;
    for (int i = tid; i < F_IN * HID; i += 256) Ws[i] = W[i];
    __syncthreads();
    int lane = tid & 63;
    int wv = tid >> 6;
    int li = lane & 31;
    int hbase = lane & 32;
    int v = blockIdx.x * 8 + wv * 2 + (lane >> 5);

    float xv = (li < F_IN) ? x[v * F_IN + li] : 0.0f;
    const float2* __restrict__ Ws2 = (const float2*)Ws;
    float o0 = 0.0f, o1 = 0.0f;
#pragma unroll
    for (int k = 0; k < F_IN; ++k) {
        float xk = __shfl(xv, hbase + k);
        float2 w = Ws2[k * 32 + li];
        o0 += xk * w.x; o1 += xk * w.y;
    }
    float dv = dinv[v];
    yb[v * 32 + li] = pack_bf2(dv * o0, dv * o1);
}

// 4-node/wave bf16 gather-aggregate over CAP-64 buckets. 16 lanes per node;
// lane's uint2 = 8 B covers feats 4*q16..4*q16+3, one gather instr = 4 full
// 128 B rows = 4 edges. col read once per layer -> NT load (don't evict the
// y-gather working set). 16 gathers in g[16] regs before accum.
// FUSE=1: epilogue applies next layer's GEMM, writes bf16 ynext.
// FUSE=0: writes fp32 h (float4) into outp4 for the pool.
template<int FUSE>
__global__ __launch_bounds__(256) void k_agg4(const uint2* __restrict__ yb2,
                                              const int* __restrict__ cnt,
                                              const int* __restrict__ col,
                                              const float* __restrict__ dinv,
                                              const float* __restrict__ b,
                                              const float* __restrict__ W,
                                              uint2* __restrict__ ybnext2,
                                              float4* __restrict__ outp4) {
    __shared__ float Ws[HID * HID];
    int tid = threadIdx.x;
    if (FUSE) {
#pragma unroll
        for (int i = 0; i < 16; ++i) Ws[tid + i * 256] = W[tid + i * 256];
        __syncthreads();
    }
    int lane = tid & 63;
    int wv = tid >> 6;
    int q16 = lane & 15;          // feature-quad id within node
    int qbase = lane & 48;        // first lane of this node's 16-lane group
    int v = blockIdx.x * 16 + wv * 4 + (lane >> 4);  // grid*16 == N_NODES

    uint2 s = yb2[v * 16 + q16];  // self-loop
    float a0 = bf_lo(s.x), a1 = bf_hi(s.x), a2 = bf_lo(s.y), a3 = bf_hi(s.y);

    int e0 = v << 6;              // bucket base
    int n = min(cnt[v], CAP);     // degree (group-uniform)
    int e1 = e0 + n;
    int m = max(n, __shfl_xor(n, 16));
    m = max(m, __shfl_xor(m, 32));
    int nch = (m + 15) >> 4;      // wave-uniform chunk count

    for (int c = 0; c < nch; ++c) {
        int base = e0 + (c << 4);
        int rem = e1 - base;       // group-uniform remaining
        int pos = base + q16;
        int iv = (pos < e1) ? __builtin_nontemporal_load(&col[pos]) : 0;
        uint2 g[16];
#pragma unroll
        for (int t = 0; t < 16; ++t) {
            int sidx = __shfl(iv, qbase + t);
            if (t < rem) g[t] = yb2[sidx * 16 + q16];
            else         g[t] = make_uint2(0u, 0u);
        }
#pragma unroll
        for (int t = 0; t < 16; ++t) {
            a0 += bf_lo(g[t].x); a1 += bf_hi(g[t].x);
            a2 += bf_lo(g[t].y); a3 += bf_hi(g[t].y);
        }
    }

    float dv = dinv[v];
    const float4* __restrict__ b4p = (const float4*)b;
    float4 bb = b4p[q16];
    float h0 = fmaxf(dv * a0 + bb.x, 0.0f);
    float h1 = fmaxf(dv * a1 + bb.y, 0.0f);
    float h2 = fmaxf(dv * a2 + bb.z, 0.0f);
    float h3 = fmaxf(dv * a3 + bb.w, 0.0f);

    if (FUSE) {
        // o[f] = sum_k h[k]*W[k][f]; feat k lives at lane qbase+(k>>2), comp k&3
        const float4* __restrict__ Ws4 = (const float4*)Ws;
        float o0 = 0.0f, o1 = 0.0f, o2 = 0.0f, o3 = 0.0f;
#pragma unroll
        for (int k = 0; k < HID; ++k) {
            float hsrc = ((k & 3) == 0) ? h0 : ((k & 3) == 1) ? h1
                       : ((k & 3) == 2) ? h2 : h3;
            float hk = __shfl(hsrc, qbase + (k >> 2));
            float4 w = Ws4[k * 16 + q16];
            o0 += hk * w.x; o1 += hk * w.y; o2 += hk * w.z; o3 += hk * w.w;
        }
        ybnext2[v * 16 + q16] =
            make_uint2(pack_bf2(dv * o0, dv * o1), pack_bf2(dv * o2, dv * o3));
    } else {
        outp4[v * 16 + q16] = make_float4(h0, h1, h2, h3);
    }
}

// ---------------- pool + head ----------------

__device__ __forceinline__ int lower_bound(const int* __restrict__ a, int n, int key) {
    int lo = 0, hi = n;
    while (lo < hi) {
        int mid = (lo + hi) >> 1;
        if (a[mid] < key) lo = mid + 1; else hi = mid;
    }
    return lo;
}

__global__ __launch_bounds__(64) void k_pool_head(const float* __restrict__ h,
                                                  const int* __restrict__ batch,
                                                  const float* __restrict__ lw1,
                                                  const float* __restrict__ lb1,
                                                  const float* __restrict__ lw2,
                                                  const float* __restrict__ lb2,
                                                  float* __restrict__ out) {
    int g = blockIdx.x;
    int lane = threadIdx.x;
    int lo = lower_bound(batch, N_NODES, g);
    int hi = lower_bound(batch, N_NODES, g + 1);
    float s = 0.0f;
    for (int v = lo; v < hi; ++v) s += h[v * HID + lane];
    float gm = s / fmaxf((float)(hi - lo), 1.0f);
    float acc = lb1[lane];
#pragma unroll
    for (int k = 0; k < HID; ++k) acc += __shfl(gm, k) * lw1[k * HID + lane];
    float t1 = fmaxf(acc, 0.0f);
    float r = t1 * lw2[lane];
#pragma unroll
    for (int off = 32; off > 0; off >>= 1) r += __shfl_xor(r, off);
    if (lane == 0) out[g] = r + lb2[0];
}

// ---------------- launch ----------------

extern "C" void kernel_launch(void* const* d_in, const int* in_sizes, int n_in,
                              void* d_out, int out_size, void* d_ws, size_t ws_size,
                              hipStream_t stream) {
    const float* x   = (const float*)d_in[0];
    const float* W1  = (const float*)d_in[1];
    const float* b1  = (const float*)d_in[2];
    const float* W2  = (const float*)d_in[3];
    const float* b2  = (const float*)d_in[4];
    const float* W3  = (const float*)d_in[5];
    const float* b3  = (const float*)d_in[6];
    const float* lw1 = (const float*)d_in[7];
    const float* lb1 = (const float*)d_in[8];
    const float* lw2 = (const float*)d_in[9];
    const float* lb2 = (const float*)d_in[10];
    const int* ei    = (const int*)d_in[11];
    const int* batch = (const int*)d_in[12];
    const int* src = ei;             // edge_index[0]
    const int* dst = ei + N_EDGES;   // edge_index[1]
    float* out = (float*)d_out;

    // workspace layout (4B units; yb offsets 8B-aligned, bufH 16B-aligned)
    int* ws = (int*)d_ws;
    int* cnt     = ws;                                 // [100000] (zeroed)
    int* col     = ws + 100000;                        // [6400000] CAP-64 buckets
    float* dinv  = (float*)(ws + 6500000);             // [100000]
    unsigned int* ybA = (unsigned int*)(ws + 6600000); // [3200000] bf16 y
    unsigned int* ybB = (unsigned int*)(ws + 9800000); // [3200000]
    float* bufH  = (float*)(ws + 13000000);            // [6400000] fp32 h3

    hipMemsetAsync(cnt, 0, N_NODES * sizeof(int), stream);

    k_fill_b<<<NCHUNK * RNG, 256, 0, stream>>>(src, dst, cnt, col);
    k_dinv<<<(N_NODES + 255) / 256, 256, 0, stream>>>(cnt, dinv);

    const int G8  = N_NODES / 8;   // 12500 (gemm1: 8 nodes/block)
    const int G16 = N_NODES / 16;  // 6250  (agg4: 16 nodes/block)

    // layer 1: x(20) -> y1 bf16 (ybA)
    k_gemm1<<<G8, 256, 0, stream>>>(x, W1, dinv, ybA);
    // layer 1 agg + layer 2 gemm: ybA -> ybB (= y2 bf16)
    k_agg4<1><<<G16, 256, 0, stream>>>((const uint2*)ybA, cnt, col, dinv, b1, W2,
                                       (uint2*)ybB, nullptr);
    // layer 2 agg + layer 3 gemm: ybB -> ybA (= y3 bf16)
    k_agg4<1><<<G16, 256, 0, stream>>>((const uint2*)ybB, cnt, col, dinv, b2, W3,
                                       (uint2*)ybA, nullptr);
    // layer 3 agg only: ybA -> bufH (fp32 h3)
    k_agg4<0><<<G16, 256, 0, stream>>>((const uint2*)ybA, cnt, col, dinv, b3, W3,
                                       nullptr, (float4*)bufH);

    // pool + head
    k_pool_head<<<N_GRAPHS, 64, 0, stream>>>(bufH, batch, lw1, lb1, lw2, lb2, out);
}